// Round 4
// baseline (218.873 us; speedup 1.0000x reference)
//
#include <hip/hip_runtime.h>
#include <hip/hip_bf16.h>

#define NUM_AGES 100
#define FEAT 512
#define BATCH 4096
#define EPSF 1e-6f
#define INV_T 10.0f
#define INV_NORM (1.0f / ((float)BATCH * (float)(BATCH - 1)))

#define BM 128
#define BN 128
#define BK 64
// kept tiles: by <= bx, bx in [0,32) -> 32*33/2 = 528; 528 = 8*66 -> bijective XCD chunking
#define NTILES 528

typedef __bf16 bf16_t;
typedef __bf16 v8bf __attribute__((ext_vector_type(8)));
typedef float v4f __attribute__((ext_vector_type(4)));

// async global->LDS, 16B per lane; LDS dest is wave-uniform base + lane*16
__device__ __forceinline__ void async16(const void* g, void* l) {
  __builtin_amdgcn_global_load_lds(
      (const __attribute__((address_space(1))) void*)g,
      (__attribute__((address_space(3))) void*)l, 16, 0, 0);
}

// ---------------- kernel 1: per-sample prep (inline rank + pre-swizzle) ---
// Block j computes rank(j) = #{k: a_k < a_j or (a_k==a_j and k<j)} (stable,
// bijective) and writes to sorted position `rank`. zb/wb are stored
// XOR-swizzled: within each 128B (64-elem) K-slab, logical 16B granule g of
// row r sits at physical position g ^ (r&7). pair_kernel's contiguous
// global_load_lds staging then lands a bank-balanced LDS layout (2 lanes per
// bank-quad = free) with zero change to its global access pattern.
__global__ __launch_bounds__(256) void prep_kernel(
    const float* __restrict__ z, const int* __restrict__ ages,
    const float* __restrict__ proxies,
    bf16_t* __restrict__ zb, bf16_t* __restrict__ wb,
    float* __restrict__ sq, float* __restrict__ hd,
    int* __restrict__ ages_s, float* __restrict__ out)
{
  int j = blockIdx.x;          // original sample index
  int t = threadIdx.x;
  if (j == 0 && t == 0) out[0] = 0.0f;   // pair_kernel accumulates into out

  int araw = ages[j];
  int a = araw < 0 ? 0 : (araw > NUM_AGES - 1 ? NUM_AGES - 1 : araw);
  const float* cc = proxies + (size_t)a * FEAT;
  const float* cn = proxies + (size_t)(a + 1 > NUM_AGES - 1 ? NUM_AGES - 1 : a + 1) * FEAT;
  const float* cp = proxies + (size_t)(a - 1 < 0 ? 0 : a - 1) * FEAT;
  const float* zr = z + (size_t)j * FEAT;

  // ---- rank of sample j in stable age order ----
  int cnt = 0;
#pragma unroll
  for (int e = 0; e < BATCH / 256; ++e) {
    int k = t + e * 256;
    int ak = ages[k];
    cnt += (ak < araw || (ak == araw && k < j)) ? 1 : 0;
  }

  // ---- vectorized per-sample math: thread t owns cols 2t, 2t+1 ----
  int c0 = 2 * t;
  float2 cc2 = *(const float2*)(cc + c0);
  float2 cn2 = *(const float2*)(cn + c0);
  float2 cp2 = *(const float2*)(cp + c0);
  float2 z2  = *(const float2*)(zr + c0);
  float df0 = cn2.x - cc2.x, df1 = cn2.y - cc2.y;
  float db0 = cp2.x - cc2.x, db1 = cp2.y - cc2.y;
  float s_ff = df0 * df0 + df1 * df1;
  float s_bb = db0 * db0 + db1 * db1;
  float s_zz = z2.x * z2.x + z2.y * z2.y;
  float s_zf = z2.x * df0 + z2.y * df1;
  float s_zb = z2.x * db0 + z2.y * db1;

  float fcnt = (float)cnt;
#pragma unroll
  for (int off = 32; off > 0; off >>= 1) {
    s_ff += __shfl_down(s_ff, off, 64);
    s_bb += __shfl_down(s_bb, off, 64);
    s_zz += __shfl_down(s_zz, off, 64);
    s_zf += __shfl_down(s_zf, off, 64);
    s_zb += __shfl_down(s_zb, off, 64);
    fcnt += __shfl_down(fcnt, off, 64);
  }
  __shared__ float red[4][6];
  int wv = t >> 6, lane = t & 63;
  if (lane == 0) {
    red[wv][0] = s_ff; red[wv][1] = s_bb; red[wv][2] = s_zz;
    red[wv][3] = s_zf; red[wv][4] = s_zb; red[wv][5] = fcnt;
  }
  __syncthreads();
  float ff = red[0][0] + red[1][0] + red[2][0] + red[3][0];
  float bb = red[0][1] + red[1][1] + red[2][1] + red[3][1];
  float zz = red[0][2] + red[1][2] + red[2][2] + red[3][2];
  float zdf = red[0][3] + red[1][3] + red[2][3] + red[3][3];
  float zdb = red[0][4] + red[1][4] + red[2][4] + red[3][4];
  int rank = (int)(red[0][5] + red[1][5] + red[2][5] + red[3][5]);

  float rf = 1.0f / (sqrtf(ff) + EPSF);
  float rb = 1.0f / (sqrtf(bb) + EPSF);
  int key = rank & 7;
  // swizzled column for the granule holding cols {2t, 2t+1}
  int c2s = (c0 & ~63) | (((((c0 >> 3) & 7) ^ key) << 3)) | (c0 & 7);
  float w0 = db0 * rb - df0 * rf;
  float w1 = db1 * rb - df1 * rf;
  union { bf16_t h[2]; unsigned u; } uz, uw;
  uz.h[0] = (bf16_t)z2.x; uz.h[1] = (bf16_t)z2.y;
  uw.h[0] = (bf16_t)w0;   uw.h[1] = (bf16_t)w1;
  *(unsigned*)((char*)zb + ((size_t)rank * FEAT + c2s) * 2) = uz.u;
  *(unsigned*)((char*)wb + ((size_t)rank * FEAT + c2s) * 2) = uw.u;
  if (t == 0) {
    sq[rank] = zz;
    hd[rank] = rb * zdb - rf * zdf;
    ages_s[rank] = araw;
  }
}

// ---------------- kernel 2: fused pairwise tile (upper-tri band only) ----
// v4: scale-up of the PROVEN round-0 schedule (stage -> sync -> compute ->
// sync, no inline-asm scaffolding: v3b's fences/setprio broke the compiler's
// ds_read/MFMA pipelining and regressed 47->58us = m196's negative arm).
//   * BN 64->128, 512 threads, 8 waves (2x4 grid); per-wave tile stays the
//     verified 64x32 -> all fragment/swizzle/epilogue math unchanged.
//   * Single 48KB buffer -> 3 blocks/CU = 24 waves/CU (6/SIMD): each block's
//     stage-drain hides under the other two blocks' MFMA phases (m114).
//   * 528 blocks (halved): per-output barriers/prologue/epilogue halved.
//   * Column-major triangular tile order, XCD-chunked (528=8*66 bijective):
//     consecutive tiles on an XCD share the Z/W panel (256KB) and walk
//     adjacent A rows -> staging is private-L2-resident (kept from v2:
//     FETCH 24.5->14.5MB measured).
__global__ __launch_bounds__(512, 6) void pair_kernel(
    const bf16_t* __restrict__ zb, const bf16_t* __restrict__ wb,
    const float* __restrict__ sq, const float* __restrict__ hd,
    const int* __restrict__ ages, float* __restrict__ out)
{
  // A: 128x64 bf16 = 16384 B | Z: 128x64 = 16384 B | W: 128x64 = 16384 B
  __shared__ __attribute__((aligned(16))) char lds[49152];
  __shared__ float s_sqi[BM];
  __shared__ int   s_agei[BM];
  __shared__ float s_sqj[BN];
  __shared__ float s_hdj[BN];
  __shared__ int   s_agej[BN];
  __shared__ float wsum[8];

  int t = threadIdx.x;
  int wv = t >> 6, lane = t & 63;

  // ---- tile decode: XCD chunk + column-major triangle (by <= bx) ----
  // column bx holds bx+1 tiles (by = 0..bx); XCD x gets ids [66x, 66x+66)
  int id = (blockIdx.x & 7) * (NTILES / 8) + (blockIdx.x >> 3);
  int bx = 0, rem = id;
  while (rem >= bx + 1) { rem -= bx + 1; ++bx; }
  int by = rem;
  int i0 = by * BM, j0 = bx * BN;

  if (t < BM) {
    s_sqi[t] = sq[i0 + t];
    s_agei[t] = ages[i0 + t];
  } else if (t < BM + BN) {
    int u = t - BM;
    s_sqj[u] = sq[j0 + u];
    s_hdj[u] = hd[j0 + u];
    s_agej[u] = ages[j0 + u];
  }

  v4f accG[4][2], accH[4][2];
#pragma unroll
  for (int a = 0; a < 4; ++a)
#pragma unroll
    for (int b = 0; b < 2; ++b) {
      accG[a][b] = (v4f){0.f, 0.f, 0.f, 0.f};
      accH[a][b] = (v4f){0.f, 0.f, 0.f, 0.f};
    }

  int wm = wv >> 2, wn = wv & 3;        // wave grid 2x4: 64 rows x 32 cols each
  int lm = lane & 15, q = lane >> 4;
  // swizzled granule byte offsets for the two 32-elem slabs (key = lm&7)
  int psw0 = ((q     ) ^ (lm & 7)) * 16;
  int psw1 = ((q + 4 ) ^ (lm & 7)) * 16;

  // staging: per async16, lane l covers row (l>>3), physical granule (l&7)
  // of an 8-row x 128B chunk (contiguous copy preserves prep's swizzle).
  int loff = (lane >> 3) * FEAT + (lane & 7) * 8;   // bf16 elements
  const bf16_t* baseA = zb + (size_t)i0 * FEAT + loff;
  const bf16_t* baseZ = zb + (size_t)j0 * FEAT + loff;
  const bf16_t* baseW = wb + (size_t)j0 * FEAT + loff;

  for (int k0 = 0; k0 < FEAT; k0 += BK) {
    // A/Z/W: 16 chunks of 8 rows each; wave wv does chunks wv*2, wv*2+1
#pragma unroll
    for (int c = 0; c < 2; ++c) {
      int chunk = wv * 2 + c;
      async16(baseA + (size_t)chunk * 8 * FEAT + k0, lds + chunk * 1024);
      async16(baseZ + (size_t)chunk * 8 * FEAT + k0, lds + 16384 + chunk * 1024);
      async16(baseW + (size_t)chunk * 8 * FEAT + k0, lds + 32768 + chunk * 1024);
    }
    __syncthreads();   // implicit vmcnt(0): tile staged

#pragma unroll
    for (int s = 0; s < 2; ++s) {
      int psw = s ? psw1 : psw0;
      v8bf afr[4], bz[2], bw[2];
#pragma unroll
      for (int mi = 0; mi < 4; ++mi) {
        int r = wm * 64 + mi * 16 + lm;
        afr[mi] = *(const v8bf*)(lds + r * 128 + psw);
      }
#pragma unroll
      for (int ni = 0; ni < 2; ++ni) {
        int r = wn * 32 + ni * 16 + lm;
        bz[ni] = *(const v8bf*)(lds + 16384 + r * 128 + psw);
        bw[ni] = *(const v8bf*)(lds + 32768 + r * 128 + psw);
      }
#pragma unroll
      for (int mi = 0; mi < 4; ++mi)
#pragma unroll
        for (int ni = 0; ni < 2; ++ni) {
          accG[mi][ni] = __builtin_amdgcn_mfma_f32_16x16x32_bf16(afr[mi], bz[ni], accG[mi][ni], 0, 0, 0);
          accH[mi][ni] = __builtin_amdgcn_mfma_f32_16x16x32_bf16(afr[mi], bw[ni], accH[mi][ni], 0, 0, 0);
        }
    }
    __syncthreads();   // WAR: reads done before next iter's staging
  }

  // epilogue: C/D layout col = lane&15 (-> j), row = q*4 + reg (-> i)
  float tsum = 0.f;
#pragma unroll
  for (int ni = 0; ni < 2; ++ni) {
    int jl = wn * 32 + ni * 16 + lm;
    float sqj = s_sqj[jl];
    float hdj = s_hdj[jl];
    int aj = s_agej[jl];
#pragma unroll
    for (int mi = 0; mi < 4; ++mi) {
#pragma unroll
      for (int r = 0; r < 4; ++r) {
        int il = wm * 64 + mi * 16 + q * 4 + r;
        float g = accG[mi][ni][r];
        float h = accH[mi][ni][r];
        float d2 = fmaxf(s_sqi[il] + sqj - 2.0f * g, 1e-12f);
        float rs = __builtin_amdgcn_rsqf(d2);
        float arg = (h - hdj) * INV_T * rs;
        float sp = fmaxf(arg, 0.0f) + __logf(1.0f + __expf(-fabsf(arg)));
        tsum += (s_agei[il] < aj) ? sp : 0.0f;
      }
    }
  }

#pragma unroll
  for (int off = 32; off > 0; off >>= 1) tsum += __shfl_down(tsum, off, 64);
  if (lane == 0) wsum[wv] = tsum;
  __syncthreads();
  if (t == 0) {
    float bs = 0.f;
#pragma unroll
    for (int w = 0; w < 8; ++w) bs += wsum[w];
    atomicAdd(out, bs * INV_NORM);
  }
}

extern "C" void kernel_launch(void* const* d_in, const int* in_sizes, int n_in,
                              void* d_out, int out_size, void* d_ws, size_t ws_size,
                              hipStream_t stream) {
  const float* z = (const float*)d_in[0];
  const int* ages = (const int*)d_in[1];
  const float* proxies = (const float*)d_in[2];
  float* out = (float*)d_out;

  char* ws = (char*)d_ws;
  bf16_t* zb = (bf16_t*)ws;                                   // 4 MB
  bf16_t* wb = (bf16_t*)(ws + (size_t)4 * 1024 * 1024);       // 4 MB
  size_t o = (size_t)8 * 1024 * 1024;
  float* sq      = (float*)(ws + o);            // 16 KB
  float* hd      = (float*)(ws + o + 16384);    // 16 KB
  int*   ages_s  = (int*)  (ws + o + 32768);    // 16 KB

  prep_kernel<<<BATCH, 256, 0, stream>>>(z, ages, proxies, zb, wb, sq, hd, ages_s, out);
  pair_kernel<<<NTILES, 512, 0, stream>>>(zb, wb, sq, hd, ages_s, out);
}

// Round 5
// 105.807 us; speedup vs baseline: 2.0686x; 2.0686x over previous
//
#include <hip/hip_runtime.h>
#include <hip/hip_bf16.h>

#define NUM_AGES 100
#define FEAT 512
#define BATCH 4096
#define EPSF 1e-6f
#define INV_T 10.0f
#define INV_NORM (1.0f / ((float)BATCH * (float)(BATCH - 1)))

#define BM 128
#define BN 128
#define BK 64
// kept tiles: by <= bx, bx in [0,32) -> 32*33/2 = 528; 528 = 8*66 -> bijective XCD chunking
#define NTILES 528

typedef __bf16 bf16_t;
typedef __bf16 v8bf __attribute__((ext_vector_type(8)));
typedef float v4f __attribute__((ext_vector_type(4)));

// async global->LDS, 16B per lane; LDS dest is wave-uniform base + lane*16
__device__ __forceinline__ void async16(const void* g, void* l) {
  __builtin_amdgcn_global_load_lds(
      (const __attribute__((address_space(1))) void*)g,
      (__attribute__((address_space(3))) void*)l, 16, 0, 0);
}

// ---------------- kernel 1: per-sample prep (inline rank + pre-swizzle) ---
// Block j computes rank(j) = #{k: a_k < a_j or (a_k==a_j and k<j)} (stable,
// bijective) and writes to sorted position `rank`. zb/wb are stored
// XOR-swizzled: within each 128B (64-elem) K-slab, logical 16B granule g of
// row r sits at physical position g ^ (r&7). pair_kernel's contiguous
// global_load_lds staging then lands a bank-balanced LDS layout (2 lanes per
// bank-quad = free) with zero change to its global access pattern.
__global__ __launch_bounds__(256) void prep_kernel(
    const float* __restrict__ z, const int* __restrict__ ages,
    const float* __restrict__ proxies,
    bf16_t* __restrict__ zb, bf16_t* __restrict__ wb,
    float* __restrict__ sq, float* __restrict__ hd,
    int* __restrict__ ages_s, float* __restrict__ out)
{
  int j = blockIdx.x;          // original sample index
  int t = threadIdx.x;
  if (j == 0 && t == 0) out[0] = 0.0f;   // pair_kernel accumulates into out

  int araw = ages[j];
  int a = araw < 0 ? 0 : (araw > NUM_AGES - 1 ? NUM_AGES - 1 : araw);
  const float* cc = proxies + (size_t)a * FEAT;
  const float* cn = proxies + (size_t)(a + 1 > NUM_AGES - 1 ? NUM_AGES - 1 : a + 1) * FEAT;
  const float* cp = proxies + (size_t)(a - 1 < 0 ? 0 : a - 1) * FEAT;
  const float* zr = z + (size_t)j * FEAT;

  // ---- rank of sample j in stable age order ----
  int cnt = 0;
#pragma unroll
  for (int e = 0; e < BATCH / 256; ++e) {
    int k = t + e * 256;
    int ak = ages[k];
    cnt += (ak < araw || (ak == araw && k < j)) ? 1 : 0;
  }

  // ---- vectorized per-sample math: thread t owns cols 2t, 2t+1 ----
  int c0 = 2 * t;
  float2 cc2 = *(const float2*)(cc + c0);
  float2 cn2 = *(const float2*)(cn + c0);
  float2 cp2 = *(const float2*)(cp + c0);
  float2 z2  = *(const float2*)(zr + c0);
  float df0 = cn2.x - cc2.x, df1 = cn2.y - cc2.y;
  float db0 = cp2.x - cc2.x, db1 = cp2.y - cc2.y;
  float s_ff = df0 * df0 + df1 * df1;
  float s_bb = db0 * db0 + db1 * db1;
  float s_zz = z2.x * z2.x + z2.y * z2.y;
  float s_zf = z2.x * df0 + z2.y * df1;
  float s_zb = z2.x * db0 + z2.y * db1;

  float fcnt = (float)cnt;
#pragma unroll
  for (int off = 32; off > 0; off >>= 1) {
    s_ff += __shfl_down(s_ff, off, 64);
    s_bb += __shfl_down(s_bb, off, 64);
    s_zz += __shfl_down(s_zz, off, 64);
    s_zf += __shfl_down(s_zf, off, 64);
    s_zb += __shfl_down(s_zb, off, 64);
    fcnt += __shfl_down(fcnt, off, 64);
  }
  __shared__ float red[4][6];
  int wv = t >> 6, lane = t & 63;
  if (lane == 0) {
    red[wv][0] = s_ff; red[wv][1] = s_bb; red[wv][2] = s_zz;
    red[wv][3] = s_zf; red[wv][4] = s_zb; red[wv][5] = fcnt;
  }
  __syncthreads();
  float ff = red[0][0] + red[1][0] + red[2][0] + red[3][0];
  float bb = red[0][1] + red[1][1] + red[2][1] + red[3][1];
  float zz = red[0][2] + red[1][2] + red[2][2] + red[3][2];
  float zdf = red[0][3] + red[1][3] + red[2][3] + red[3][3];
  float zdb = red[0][4] + red[1][4] + red[2][4] + red[3][4];
  int rank = (int)(red[0][5] + red[1][5] + red[2][5] + red[3][5]);

  float rf = 1.0f / (sqrtf(ff) + EPSF);
  float rb = 1.0f / (sqrtf(bb) + EPSF);
  int key = rank & 7;
  // swizzled column for the granule holding cols {2t, 2t+1}
  int c2s = (c0 & ~63) | (((((c0 >> 3) & 7) ^ key) << 3)) | (c0 & 7);
  float w0 = db0 * rb - df0 * rf;
  float w1 = db1 * rb - df1 * rf;
  union { bf16_t h[2]; unsigned u; } uz, uw;
  uz.h[0] = (bf16_t)z2.x; uz.h[1] = (bf16_t)z2.y;
  uw.h[0] = (bf16_t)w0;   uw.h[1] = (bf16_t)w1;
  *(unsigned*)((char*)zb + ((size_t)rank * FEAT + c2s) * 2) = uz.u;
  *(unsigned*)((char*)wb + ((size_t)rank * FEAT + c2s) * 2) = uw.u;
  if (t == 0) {
    sq[rank] = zz;
    hd[rank] = rb * zdb - rf * zdf;
    ages_s[rank] = araw;
  }
}

// ---------------- kernel 2: fused pairwise tile (upper-tri band only) ----
// v5 = v4 with the occupancy bug fixed. v4's __launch_bounds__(512,6)
// demanded 6 waves/EU -> unified VGPR budget 512/6~85 regs, but the wave
// needs ~124 (64 AGPR acc + ~60 VGPR, = round-0's allocation). Result was
// accumulator spill to scratch: VGPR_Count=40, WRITE_SIZE 280MB (!) from a
// kernel that stores 4 bytes, MfmaUtil 0.2-4%, pair 153us.
// (512,4) caps at 128 regs >= 124 needed -> no spill; 4 waves/EU =
// 2 blocks/CU = 16 waves/CU (same TLP as round-0's 4x256t blocks, but:
//   * A-panel reused by 4 column-waves -> 48KB staged per 256 wave-MFMAs
//     vs round-0's 32KB per 128 (1.33x better L2-traffic ratio)
//   * half the barrier events per CU
//   * XCD-chunked triangular order kept (proven: FETCH 24.5->14.5MB))
// Schedule stays the PROVEN plain stage->sync->compute->sync (no inline-asm
// fences: v3b showed they break compiler pipelining and regress).
__global__ __launch_bounds__(512, 4) void pair_kernel(
    const bf16_t* __restrict__ zb, const bf16_t* __restrict__ wb,
    const float* __restrict__ sq, const float* __restrict__ hd,
    const int* __restrict__ ages, float* __restrict__ out)
{
  // A: 128x64 bf16 = 16384 B | Z: 128x64 = 16384 B | W: 128x64 = 16384 B
  __shared__ __attribute__((aligned(16))) char lds[49152];
  __shared__ float s_sqi[BM];
  __shared__ int   s_agei[BM];
  __shared__ float s_sqj[BN];
  __shared__ float s_hdj[BN];
  __shared__ int   s_agej[BN];
  __shared__ float wsum[8];

  int t = threadIdx.x;
  int wv = t >> 6, lane = t & 63;

  // ---- tile decode: XCD chunk + column-major triangle (by <= bx) ----
  // column bx holds bx+1 tiles (by = 0..bx); XCD x gets ids [66x, 66x+66)
  int id = (blockIdx.x & 7) * (NTILES / 8) + (blockIdx.x >> 3);
  int bx = 0, rem = id;
  while (rem >= bx + 1) { rem -= bx + 1; ++bx; }
  int by = rem;
  int i0 = by * BM, j0 = bx * BN;

  if (t < BM) {
    s_sqi[t] = sq[i0 + t];
    s_agei[t] = ages[i0 + t];
  } else if (t < BM + BN) {
    int u = t - BM;
    s_sqj[u] = sq[j0 + u];
    s_hdj[u] = hd[j0 + u];
    s_agej[u] = ages[j0 + u];
  }

  v4f accG[4][2], accH[4][2];
#pragma unroll
  for (int a = 0; a < 4; ++a)
#pragma unroll
    for (int b = 0; b < 2; ++b) {
      accG[a][b] = (v4f){0.f, 0.f, 0.f, 0.f};
      accH[a][b] = (v4f){0.f, 0.f, 0.f, 0.f};
    }

  int wm = wv >> 2, wn = wv & 3;        // wave grid 2x4: 64 rows x 32 cols each
  int lm = lane & 15, q = lane >> 4;
  // swizzled granule byte offsets for the two 32-elem slabs (key = lm&7)
  int psw0 = ((q     ) ^ (lm & 7)) * 16;
  int psw1 = ((q + 4 ) ^ (lm & 7)) * 16;

  // staging: per async16, lane l covers row (l>>3), physical granule (l&7)
  // of an 8-row x 128B chunk (contiguous copy preserves prep's swizzle).
  int loff = (lane >> 3) * FEAT + (lane & 7) * 8;   // bf16 elements
  const bf16_t* baseA = zb + (size_t)i0 * FEAT + loff;
  const bf16_t* baseZ = zb + (size_t)j0 * FEAT + loff;
  const bf16_t* baseW = wb + (size_t)j0 * FEAT + loff;

  for (int k0 = 0; k0 < FEAT; k0 += BK) {
    // A/Z/W: 16 chunks of 8 rows each; wave wv does chunks wv*2, wv*2+1
#pragma unroll
    for (int c = 0; c < 2; ++c) {
      int chunk = wv * 2 + c;
      async16(baseA + (size_t)chunk * 8 * FEAT + k0, lds + chunk * 1024);
      async16(baseZ + (size_t)chunk * 8 * FEAT + k0, lds + 16384 + chunk * 1024);
      async16(baseW + (size_t)chunk * 8 * FEAT + k0, lds + 32768 + chunk * 1024);
    }
    __syncthreads();   // implicit vmcnt(0): tile staged

#pragma unroll
    for (int s = 0; s < 2; ++s) {
      int psw = s ? psw1 : psw0;
      v8bf afr[4], bz[2], bw[2];
#pragma unroll
      for (int mi = 0; mi < 4; ++mi) {
        int r = wm * 64 + mi * 16 + lm;
        afr[mi] = *(const v8bf*)(lds + r * 128 + psw);
      }
#pragma unroll
      for (int ni = 0; ni < 2; ++ni) {
        int r = wn * 32 + ni * 16 + lm;
        bz[ni] = *(const v8bf*)(lds + 16384 + r * 128 + psw);
        bw[ni] = *(const v8bf*)(lds + 32768 + r * 128 + psw);
      }
#pragma unroll
      for (int mi = 0; mi < 4; ++mi)
#pragma unroll
        for (int ni = 0; ni < 2; ++ni) {
          accG[mi][ni] = __builtin_amdgcn_mfma_f32_16x16x32_bf16(afr[mi], bz[ni], accG[mi][ni], 0, 0, 0);
          accH[mi][ni] = __builtin_amdgcn_mfma_f32_16x16x32_bf16(afr[mi], bw[ni], accH[mi][ni], 0, 0, 0);
        }
    }
    __syncthreads();   // WAR: reads done before next iter's staging
  }

  // epilogue: C/D layout col = lane&15 (-> j), row = q*4 + reg (-> i)
  float tsum = 0.f;
#pragma unroll
  for (int ni = 0; ni < 2; ++ni) {
    int jl = wn * 32 + ni * 16 + lm;
    float sqj = s_sqj[jl];
    float hdj = s_hdj[jl];
    int aj = s_agej[jl];
#pragma unroll
    for (int mi = 0; mi < 4; ++mi) {
#pragma unroll
      for (int r = 0; r < 4; ++r) {
        int il = wm * 64 + mi * 16 + q * 4 + r;
        float g = accG[mi][ni][r];
        float h = accH[mi][ni][r];
        float d2 = fmaxf(s_sqi[il] + sqj - 2.0f * g, 1e-12f);
        float rs = __builtin_amdgcn_rsqf(d2);
        float arg = (h - hdj) * INV_T * rs;
        float sp = fmaxf(arg, 0.0f) + __logf(1.0f + __expf(-fabsf(arg)));
        tsum += (s_agei[il] < aj) ? sp : 0.0f;
      }
    }
  }

#pragma unroll
  for (int off = 32; off > 0; off >>= 1) tsum += __shfl_down(tsum, off, 64);
  if (lane == 0) wsum[wv] = tsum;
  __syncthreads();
  if (t == 0) {
    float bs = 0.f;
#pragma unroll
    for (int w = 0; w < 8; ++w) bs += wsum[w];
    atomicAdd(out, bs * INV_NORM);
  }
}

extern "C" void kernel_launch(void* const* d_in, const int* in_sizes, int n_in,
                              void* d_out, int out_size, void* d_ws, size_t ws_size,
                              hipStream_t stream) {
  const float* z = (const float*)d_in[0];
  const int* ages = (const int*)d_in[1];
  const float* proxies = (const float*)d_in[2];
  float* out = (float*)d_out;

  char* ws = (char*)d_ws;
  bf16_t* zb = (bf16_t*)ws;                                   // 4 MB
  bf16_t* wb = (bf16_t*)(ws + (size_t)4 * 1024 * 1024);       // 4 MB
  size_t o = (size_t)8 * 1024 * 1024;
  float* sq      = (float*)(ws + o);            // 16 KB
  float* hd      = (float*)(ws + o + 16384);    // 16 KB
  int*   ages_s  = (int*)  (ws + o + 32768);    // 16 KB

  prep_kernel<<<BATCH, 256, 0, stream>>>(z, ages, proxies, zb, wb, sq, hd, ages_s, out);
  pair_kernel<<<NTILES, 512, 0, stream>>>(zb, wb, sq, hd, ages_s, out);
}